// Round 1
// baseline (303.644 us; speedup 1.0000x reference)
//
#include <hip/hip_runtime.h>
#include <hip/hip_bf16.h>
#include <stdint.h>

// LightningIndexer: importance[b,q,k] = sum_h w[b,q,h] * relu( qh[b,q,:] . kv[b,k,:] )
// B=2, T=4096, C=2048, H=16, D=32.
// Pipeline: (1) cast x + pack W -> bf16, (2) MFMA GEMM projections, (3) fused score kernel.
// Workspace use: ~47.2 MB (xb 32MiB | Wp 2.5MiB | qkw 10MiB | w_f32 0.5MiB).

typedef __attribute__((ext_vector_type(8))) short bf16x8;
typedef __attribute__((ext_vector_type(4))) float f32x4;

#define NPAD 640   // 512 q cols + 32 k cols + 16 w cols + 80 zero pad (5 tiles of 128)
#define KCOL 512
#define WCOL 544

__device__ __forceinline__ unsigned short f2bf(float f) {
  union { float f; unsigned u; } c; c.f = f;
  unsigned u = c.u;
  u += 0x7FFFu + ((u >> 16) & 1u);   // round-to-nearest-even
  return (unsigned short)(u >> 16);
}

__device__ __forceinline__ void async_copy16(void* lds, const void* g) {
  __builtin_amdgcn_global_load_lds(
      (const __attribute__((address_space(1))) unsigned*)g,
      (__attribute__((address_space(3))) unsigned*)lds, 16, 0, 0);
}

// ---------------- kernel 1: cast x to bf16, pack Wq/Wk/Ww (+zero pad) ----------------
__global__ __launch_bounds__(256) void pack_kernel(
    const float* __restrict__ x, const float* __restrict__ Wq,
    const float* __restrict__ Wk, const float* __restrict__ Ww,
    unsigned short* __restrict__ xb, unsigned short* __restrict__ Wp) {
  const int64_t NX4 = 16777216 / 4;          // x float4 count
  int64_t i = (int64_t)blockIdx.x * 256 + threadIdx.x;
  if (i < NX4) {
    float4 v = ((const float4*)x)[i];
    ushort4 o;
    o.x = f2bf(v.x); o.y = f2bf(v.y); o.z = f2bf(v.z); o.w = f2bf(v.w);
    ((ushort4*)xb)[i] = o;
  } else {
    int p = (int)(i - NX4);                  // 0 .. 640*2048/4-1 = 327679
    int row = p >> 9;                        // 512 float4 per 2048-col row
    int col = (p & 511) << 2;
    float4 v = make_float4(0.f, 0.f, 0.f, 0.f);
    if (row < 512)      v = *(const float4*)(Wq + (int64_t)row * 2048 + col);
    else if (row < 544) v = *(const float4*)(Wk + (int64_t)(row - 512) * 2048 + col);
    else if (row < 560) v = *(const float4*)(Ww + (int64_t)(row - 544) * 2048 + col);
    ushort4 o;
    o.x = f2bf(v.x); o.y = f2bf(v.y); o.z = f2bf(v.z); o.w = f2bf(v.w);
    ((ushort4*)Wp)[p] = o;
  }
}

// ---------------- kernel 2: qkw = x @ Wp^T  (8192 x 640 x 2048, bf16 MFMA) ----------------
__global__ __launch_bounds__(256) void gemm_proj(
    const unsigned short* __restrict__ xb, const unsigned short* __restrict__ Wp,
    unsigned short* __restrict__ qkwb, float* __restrict__ wf) {
  __shared__ short lds_a[128 * 32];
  __shared__ short lds_b[128 * 32];
  const int tid = threadIdx.x;
  const int lane = tid & 63;
  const int l15 = lane & 15, quad = lane >> 4;
  const int wave = tid >> 6;
  const int wm = wave >> 1, wn = wave & 1;
  const int m0 = blockIdx.y * 128, n0 = blockIdx.x * 128;

  const int c0 = tid, c1 = tid + 256;        // 16B chunk ids, 512 per tile
  const unsigned short* ga0 = xb + (int64_t)(m0 + (c0 >> 2)) * 2048 + (c0 & 3) * 8;
  const unsigned short* ga1 = xb + (int64_t)(m0 + (c1 >> 2)) * 2048 + (c1 & 3) * 8;
  const unsigned short* gb0 = Wp + (int64_t)(n0 + (c0 >> 2)) * 2048 + (c0 & 3) * 8;
  const unsigned short* gb1 = Wp + (int64_t)(n0 + (c1 >> 2)) * 2048 + (c1 & 3) * 8;

  f32x4 acc[4][4] = {};

  for (int kt = 0; kt < 64; ++kt) {
    const int ko = kt * 32;
    async_copy16(&lds_a[c0 * 8], ga0 + ko);
    async_copy16(&lds_a[c1 * 8], ga1 + ko);
    async_copy16(&lds_b[c0 * 8], gb0 + ko);
    async_copy16(&lds_b[c1 * 8], gb1 + ko);
    __syncthreads();
    bf16x8 af[4], bfr[4];
#pragma unroll
    for (int i = 0; i < 4; ++i)
      af[i] = *(const bf16x8*)&lds_a[(wm * 64 + i * 16 + l15) * 32 + quad * 8];
#pragma unroll
    for (int j = 0; j < 4; ++j)
      bfr[j] = *(const bf16x8*)&lds_b[(wn * 64 + j * 16 + l15) * 32 + quad * 8];
#pragma unroll
    for (int i = 0; i < 4; ++i)
#pragma unroll
      for (int j = 0; j < 4; ++j)
        acc[i][j] = __builtin_amdgcn_mfma_f32_16x16x32_bf16(af[i], bfr[j], acc[i][j], 0, 0, 0);
    __syncthreads();
  }

#pragma unroll
  for (int i = 0; i < 4; ++i)
#pragma unroll
    for (int j = 0; j < 4; ++j)
#pragma unroll
      for (int r = 0; r < 4; ++r) {
        int m = m0 + wm * 64 + i * 16 + quad * 4 + r;
        int n = n0 + wn * 64 + j * 16 + l15;
        float v = acc[i][j][r];
        qkwb[(int64_t)m * NPAD + n] = f2bf(v);
        if (n >= WCOL && n < WCOL + 16) wf[m * 16 + (n - WCOL)] = v;  // w kept fp32
      }
}

// ---------------- kernel 3: fused scores ----------------
// Block: 128 k x 128 q tile (transposed compute: D row = k, D col = q so that
// w[q,h] is uniform per lane-column and stores vectorize along k).
__global__ __launch_bounds__(256) void scores_kernel(
    const unsigned short* __restrict__ qkwb, const float* __restrict__ wf,
    float* __restrict__ out) {
  const int kt = blockIdx.x, qt = blockIdx.y, b = blockIdx.z;
  const int tid = threadIdx.x;
  const int lane = tid & 63;
  const int l15 = lane & 15, quad = lane >> 4;
  const int wave = tid >> 6;
  const int wk = wave & 1, wq = wave >> 1;

  __shared__ float w_lds[16][132];           // [h][q_local], padded

  const int qrow0 = b * 4096 + qt * 128;
  const int krow0 = b * 4096 + kt * 128;

  // stage w tile transposed: 128 rows x 16 heads fp32 = 8 KB contiguous
  {
    const float4* ws = (const float4*)(wf + (int64_t)qrow0 * 16);
#pragma unroll
    for (int r = 0; r < 2; ++r) {
      int f = tid * 2 + r;                   // 0..511 float4s
      float4 v = ws[f];
      int row = f >> 2, hb = (f & 3) * 4;
      w_lds[hb + 0][row] = v.x; w_lds[hb + 1][row] = v.y;
      w_lds[hb + 2][row] = v.z; w_lds[hb + 3][row] = v.w;
    }
  }

  // K fragments: shared across all 16 heads, kept in registers
  bf16x8 ka[4];
#pragma unroll
  for (int i = 0; i < 4; ++i) {
    int kk = krow0 + wk * 64 + i * 16 + l15;
    ka[i] = *(const bf16x8*)&qkwb[(int64_t)kk * NPAD + KCOL + quad * 8];
  }

  const unsigned short* qbase =
      qkwb + (int64_t)(qrow0 + wq * 64 + l15) * NPAD + quad * 8;

  f32x4 acc[4][4] = {};
  __syncthreads();

  bf16x8 qc[4], qn[4];
#pragma unroll
  for (int j = 0; j < 4; ++j) qc[j] = *(const bf16x8*)&qbase[(int64_t)j * 16 * NPAD];

  for (int h = 0; h < 16; ++h) {
    if (h < 15) {
#pragma unroll
      for (int j = 0; j < 4; ++j)
        qn[j] = *(const bf16x8*)&qbase[(int64_t)j * 16 * NPAD + (h + 1) * 32];
    }
    float wv[4];
#pragma unroll
    for (int j = 0; j < 4; ++j) wv[j] = w_lds[h][wq * 64 + j * 16 + l15];
#pragma unroll
    for (int i = 0; i < 4; ++i)
#pragma unroll
      for (int j = 0; j < 4; ++j) {
        f32x4 z = {0.f, 0.f, 0.f, 0.f};
        f32x4 t = __builtin_amdgcn_mfma_f32_16x16x32_bf16(ka[i], qc[j], z, 0, 0, 0);
#pragma unroll
        for (int r = 0; r < 4; ++r)
          acc[i][j][r] += fmaxf(t[r], 0.f) * wv[j];
      }
#pragma unroll
    for (int j = 0; j < 4; ++j) qc[j] = qn[j];
  }

  // store: per (i,j) one dwordx4 along k
#pragma unroll
  for (int i = 0; i < 4; ++i)
#pragma unroll
    for (int j = 0; j < 4; ++j) {
      int q = qt * 128 + wq * 64 + j * 16 + l15;
      int k = kt * 128 + wk * 64 + i * 16 + quad * 4;
      float4 v = make_float4(acc[i][j][0], acc[i][j][1], acc[i][j][2], acc[i][j][3]);
      *(float4*)&out[((int64_t)b * 4096 + q) * 4096 + k] = v;
    }
}

extern "C" void kernel_launch(void* const* d_in, const int* in_sizes, int n_in,
                              void* d_out, int out_size, void* d_ws, size_t ws_size,
                              hipStream_t stream) {
  const float* x  = (const float*)d_in[0];
  const float* Wq = (const float*)d_in[1];
  const float* Wk = (const float*)d_in[2];
  const float* Ww = (const float*)d_in[3];
  float* out = (float*)d_out;

  char* ws = (char*)d_ws;
  unsigned short* xb   = (unsigned short*)ws;                 // 8192x2048 bf16 = 33,554,432 B
  unsigned short* Wp   = (unsigned short*)(ws + 33554432);    // 640x2048 bf16  =  2,621,440 B
  unsigned short* qkwb = (unsigned short*)(ws + 36175872);    // 8192x640 bf16  = 10,485,760 B
  float*          wf   = (float*)(ws + 46661632);             // 8192x16 fp32   =    524,288 B

  pack_kernel<<<17664, 256, 0, stream>>>(x, Wq, Wk, Ww, xb, Wp);
  gemm_proj<<<dim3(5, 64), 256, 0, stream>>>(xb, Wp, qkwb, wf);
  scores_kernel<<<dim3(32, 32, 2), 256, 0, stream>>>(qkwb, wf, out);
}